// Round 8
// baseline (58.683 us; speedup 1.0000x reference)
//
#include <hip/hip_runtime.h>
#include <math.h>

#define NPTS 8192
#define MPTS 8192
#define LATENT 64
#define TI 32          // rows per block tile
#define BLK 256        // threads per block
#define COLS_PER_T 4   // columns per thread (float4 store)

typedef float f32x4 __attribute__((ext_vector_type(4)));

// Workspace layout (floats):
//   xt4 : [NPTS]  float4 (x0,x1,x2,sx)   @ 0          (128 KB)
//   xxv : [NPTS]  float  ||x||^2         @ 32768      ( 32 KB)
//   yt4 : [MPTS]  float4 (y0,y1,y2,sy)   @ 40960      (128 KB)
//   yyv : [MPTS]  float  ||y||^2         @ 73728      ( 32 KB)
#define WS_XT4 0
#define WS_XXV 32768
#define WS_YT4 40960
#define WS_YYV 73728

// ---------------------------------------------------------------------------
// Kernel 1: per-point lengthscale MLP + table packing.
//   s(p) = softplus( W2 @ selu(W1 @ p + b1) + b2 )
// One thread per point; writes packed (coords, s) float4 + squared-norm.
// ---------------------------------------------------------------------------
__global__ __launch_bounds__(256)
void nsm_scale_kernel(const float* __restrict__ x,
                      const float* __restrict__ y,
                      const float* __restrict__ W1,
                      const float* __restrict__ b1,
                      const float* __restrict__ W2,
                      const float* __restrict__ b2,
                      float* __restrict__ ws) {
    int i = blockIdx.x * blockDim.x + threadIdx.x;
    if (i >= NPTS + MPTS) return;
    const float* p = (i < NPTS) ? (x + 3 * i) : (y + 3 * (i - NPTS));
    float p0 = p[0], p1 = p[1], p2 = p[2];

    const float kScale = 1.0507009873554805f;   // selu scale
    const float kAlpha = 1.6732632423543772f;   // selu alpha

    float acc = b2[0];
#pragma unroll 16
    for (int l = 0; l < LATENT; ++l) {
        float h = b1[l];
        h = fmaf(W1[3 * l + 0], p0, h);
        h = fmaf(W1[3 * l + 1], p1, h);
        h = fmaf(W1[3 * l + 2], p2, h);
        float sh = (h > 0.0f) ? (kScale * h)
                              : (kScale * kAlpha * (__expf(h) - 1.0f));
        acc = fmaf(W2[l], sh, acc);
    }
    // numerically-stable softplus: log1p(exp(-|x|)) + max(x,0)
    float sp = fmaxf(acc, 0.0f) + log1pf(__expf(-fabsf(acc)));
    float nn = fmaf(p0, p0, fmaf(p1, p1, p2 * p2));

    if (i < NPTS) {
        reinterpret_cast<float4*>(ws + WS_XT4)[i] = make_float4(p0, p1, p2, sp);
        (ws + WS_XXV)[i] = nn;
    } else {
        int j = i - NPTS;
        reinterpret_cast<float4*>(ws + WS_YT4)[j] = make_float4(p0, p1, p2, sp);
        (ws + WS_YYV)[j] = nn;
    }
}

// ---------------------------------------------------------------------------
// Kernel 2: fused pairwise Matern-5/2 tile kernel — LDS-free.
// Block tile: TI=32 rows x 1024 cols. Row data (x0,x1,x2,sx,xx) is
// wave-uniform (blockIdx-derived address) -> compiler emits s_load into
// SGPRs; no LDS staging, no __syncthreads, no ds_read in the loop.
// Column data: 5 coalesced float4 loads from L2-resident packed tables.
// Output: one nontemporal float4 per thread per row.
// ---------------------------------------------------------------------------
__global__ __launch_bounds__(BLK)
void nsm_matern_kernel(const float* __restrict__ ws,
                       float* __restrict__ out) {
    const int rowBase = blockIdx.y * TI;
    const int colBase = blockIdx.x * (BLK * COLS_PER_T) + threadIdx.x * COLS_PER_T;

    const float4* xt4 = reinterpret_cast<const float4*>(ws + WS_XT4);
    const float*  xxv = ws + WS_XXV;
    const float4* yt4 = reinterpret_cast<const float4*>(ws + WS_YT4);
    const f32x4*  yy4 = reinterpret_cast<const f32x4*>(ws + WS_YYV);

    // ---- per-thread column data: 4 cols = 4x float4 + 1x float4, coalesced ----
    float4 cw[COLS_PER_T];   // (y0, y1, y2, sy) per column
#pragma unroll
    for (int c = 0; c < COLS_PER_T; ++c) cw[c] = yt4[colBase + c];
    f32x4 yy = yy4[colBase / 4];
    float yyA[COLS_PER_T] = {yy.x, yy.y, yy.z, yy.w};

    const float sq5 = 2.2360679774997896f;     // sqrt(5)
    const float c53 = 5.0f / 3.0f;
    const float cE  = -3.2262751842f;          // -sqrt(5)*log2(e): exp(-sq5*u)=exp2(cE*u)

    f32x4* outp = reinterpret_cast<f32x4*>(out) +
                  (size_t)rowBase * (MPTS / 4) + (colBase / 4);

#pragma unroll 4
    for (int r = 0; r < TI; ++r) {
        float4 xv = xt4[rowBase + r];   // uniform address -> s_load (SGPR broadcast)
        float  xx = xxv[rowBase + r];   // uniform -> s_load
        float  res[COLS_PER_T];
#pragma unroll
        for (int c = 0; c < COLS_PER_T; ++c) {
            float dot = fmaf(xv.x, cw[c].x,
                        fmaf(xv.y, cw[c].y, xv.z * cw[c].z));
            float r2  = fmaf(-2.0f, dot, xx + yyA[c]);
            // raw v_sqrt_f32 (~1.5 ulp); threshold is 2e-2, this is noise.
            float u   = __builtin_amdgcn_sqrtf(fmaxf(r2, 1e-12f))
                        * (xv.w + cw[c].w);                 // u = r * (sx+sy)
            // poly = 1 + sqrt5*u + (5/3)*u^2, Horner: 2 FMAs
            float poly = fmaf(fmaf(c53, u, sq5), u, 1.0f);
            float e    = __builtin_amdgcn_exp2f(cE * u);    // exp(-sqrt5*u)
            res[c] = poly * e;
        }
        f32x4 v = {res[0], res[1], res[2], res[3]};
        __builtin_nontemporal_store(v, outp);
        outp += MPTS / 4;  // next row
    }
}

// ---------------------------------------------------------------------------
extern "C" void kernel_launch(void* const* d_in, const int* in_sizes, int n_in,
                              void* d_out, int out_size, void* d_ws, size_t ws_size,
                              hipStream_t stream) {
    const float* x  = (const float*)d_in[0];
    const float* y  = (const float*)d_in[1];
    const float* W1 = (const float*)d_in[2];
    const float* b1 = (const float*)d_in[3];
    const float* W2 = (const float*)d_in[4];
    const float* b2 = (const float*)d_in[5];
    float* out = (float*)d_out;
    float* ws  = (float*)d_ws;   // 320 KB of packed tables

    // Kernel 1: per-point scales + packed tables
    {
        int total = NPTS + MPTS;
        int blocks = (total + 255) / 256;
        nsm_scale_kernel<<<blocks, 256, 0, stream>>>(x, y, W1, b1, W2, b2, ws);
    }

    // Kernel 2: fused pairwise kernel matrix
    {
        dim3 grid(MPTS / (BLK * COLS_PER_T), NPTS / TI);  // (8, 256)
        dim3 block(BLK);
        nsm_matern_kernel<<<grid, block, 0, stream>>>(ws, out);
    }
}

// Round 9
// 58.286 us; speedup vs baseline: 1.0068x; 1.0068x over previous
//
#include <hip/hip_runtime.h>
#include <math.h>

#define NPTS 8192
#define MPTS 8192
#define LATENT 64
#define TI 32          // rows per block tile
#define BLK 256        // threads per block
#define COLS_PER_T 4   // columns per thread (float4 store)

typedef float f32x4 __attribute__((ext_vector_type(4)));

// ---------------------------------------------------------------------------
// Kernel 1: per-point lengthscale MLP
//   s(p) = softplus( W2 @ selu(W1 @ p + b1) + b2 )
// One thread per point; x points first, then y points, into s_all[N+M].
// ---------------------------------------------------------------------------
__global__ __launch_bounds__(256)
void nsm_scale_kernel(const float* __restrict__ x,
                      const float* __restrict__ y,
                      const float* __restrict__ W1,
                      const float* __restrict__ b1,
                      const float* __restrict__ W2,
                      const float* __restrict__ b2,
                      float* __restrict__ s_all) {
    int i = blockIdx.x * blockDim.x + threadIdx.x;
    if (i >= NPTS + MPTS) return;
    const float* p = (i < NPTS) ? (x + 3 * i) : (y + 3 * (i - NPTS));
    float p0 = p[0], p1 = p[1], p2 = p[2];

    const float kScale = 1.0507009873554805f;   // selu scale
    const float kAlpha = 1.6732632423543772f;   // selu alpha

    float acc = b2[0];
#pragma unroll 16
    for (int l = 0; l < LATENT; ++l) {
        float h = b1[l];
        h = fmaf(W1[3 * l + 0], p0, h);
        h = fmaf(W1[3 * l + 1], p1, h);
        h = fmaf(W1[3 * l + 2], p2, h);
        float sh = (h > 0.0f) ? (kScale * h)
                              : (kScale * kAlpha * (__expf(h) - 1.0f));
        acc = fmaf(W2[l], sh, acc);
    }
    // numerically-stable softplus: log1p(exp(-|x|)) + max(x,0)
    float sp = fmaxf(acc, 0.0f) + log1pf(__expf(-fabsf(acc)));
    s_all[i] = sp;
}

// ---------------------------------------------------------------------------
// Kernel 2: fused pairwise Matern-5/2 tile kernel (round-5 structure).
// SINGLE-VARIABLE CHANGE vs round 5: 1D grid of 2048 blocks with explicit
// XCD decode. Dispatch order round-robins XCDs (xcd = id%8); we assign each
// XCD a CONTIGUOUS 1024-row band (32 MB of output) instead of the default
// scattered column stripe — tests whether per-XCD write-address locality
// closes the 5.2 vs 7.0 TB/s write-stream gap.
// ---------------------------------------------------------------------------
__global__ __launch_bounds__(BLK)
void nsm_matern_kernel(const float* __restrict__ x,
                       const float* __restrict__ y,
                       const float* __restrict__ s_all,
                       float* __restrict__ out) {
    __shared__ float4 lx[TI];   // (x0, x1, x2, sx)
    __shared__ float  lxx[TI];  // ||x||^2

    // XCD-band decode: xcd = dispatch-order % 8 owns row-tiles [xcd*32, xcd*32+32)
    const int id        = blockIdx.x;      // 0..2047
    const int xcd       = id & 7;
    const int j         = id >> 3;         // 0..255
    const int rowTile   = xcd * 32 + (j >> 3);   // 0..255 (bijective)
    const int colStripe = j & 7;                 // 0..7

    const int rowBase = rowTile * TI;
    const int colBase = colStripe * (BLK * COLS_PER_T) + threadIdx.x * COLS_PER_T;

    // ---- stage TI rows into LDS ----
    if (threadIdx.x < TI) {
        int r = rowBase + threadIdx.x;
        float a0 = x[3 * r + 0];
        float a1 = x[3 * r + 1];
        float a2 = x[3 * r + 2];
        lx[threadIdx.x]  = make_float4(a0, a1, a2, s_all[r]);
        lxx[threadIdx.x] = fmaf(a0, a0, fmaf(a1, a1, a2 * a2));
    }

    // ---- per-thread column data: 4 columns = 12 consecutive floats, aligned ----
    const float4* yp = reinterpret_cast<const float4*>(y + 3 * colBase);
    float4 q0 = yp[0];
    float4 q1 = yp[1];
    float4 q2 = yp[2];
    float cy[COLS_PER_T][3] = {
        {q0.x, q0.y, q0.z},
        {q0.w, q1.x, q1.y},
        {q1.z, q1.w, q2.x},
        {q2.y, q2.z, q2.w},
    };
    float4 s4 = *reinterpret_cast<const float4*>(s_all + NPTS + colBase);
    float syA[COLS_PER_T] = {s4.x, s4.y, s4.z, s4.w};
    float yyA[COLS_PER_T];
#pragma unroll
    for (int c = 0; c < COLS_PER_T; ++c) {
        yyA[c] = fmaf(cy[c][0], cy[c][0],
                 fmaf(cy[c][1], cy[c][1], cy[c][2] * cy[c][2]));
    }

    __syncthreads();

    const float sq5 = 2.2360679774997896f;     // sqrt(5)
    const float c53 = 5.0f / 3.0f;
    const float cE  = -3.2262751842f;          // -sqrt(5)*log2(e): exp(-sq5*u)=exp2(cE*u)

    f32x4* outp = reinterpret_cast<f32x4*>(out) +
                  (size_t)rowBase * (MPTS / 4) + (colBase / 4);

#pragma unroll 4
    for (int r = 0; r < TI; ++r) {
        float4 xv = lx[r];       // broadcast (all lanes same addr -> no conflict)
        float  xx = lxx[r];
        float  res[COLS_PER_T];
#pragma unroll
        for (int c = 0; c < COLS_PER_T; ++c) {
            float dot = fmaf(xv.x, cy[c][0],
                        fmaf(xv.y, cy[c][1], xv.z * cy[c][2]));
            float r2  = fmaf(-2.0f, dot, xx + yyA[c]);
            // raw v_sqrt_f32 (~1.5 ulp); threshold is 2e-2, this is noise.
            float u   = __builtin_amdgcn_sqrtf(fmaxf(r2, 1e-12f))
                        * (xv.w + syA[c]);                  // u = r * (sx+sy)
            // poly = 1 + sqrt5*u + (5/3)*u^2, Horner: 2 FMAs
            float poly = fmaf(fmaf(c53, u, sq5), u, 1.0f);
            float e    = __builtin_amdgcn_exp2f(cE * u);    // exp(-sqrt5*u)
            res[c] = poly * e;
        }
        f32x4 v = {res[0], res[1], res[2], res[3]};
        __builtin_nontemporal_store(v, outp);
        outp += MPTS / 4;  // next row
    }
}

// ---------------------------------------------------------------------------
extern "C" void kernel_launch(void* const* d_in, const int* in_sizes, int n_in,
                              void* d_out, int out_size, void* d_ws, size_t ws_size,
                              hipStream_t stream) {
    const float* x  = (const float*)d_in[0];
    const float* y  = (const float*)d_in[1];
    const float* W1 = (const float*)d_in[2];
    const float* b1 = (const float*)d_in[3];
    const float* W2 = (const float*)d_in[4];
    const float* b2 = (const float*)d_in[5];
    float* out   = (float*)d_out;
    float* s_all = (float*)d_ws;   // (NPTS + MPTS) floats = 64 KB

    // Kernel 1: per-point scales
    {
        int total = NPTS + MPTS;
        int blocks = (total + 255) / 256;
        nsm_scale_kernel<<<blocks, 256, 0, stream>>>(x, y, W1, b1, W2, b2, s_all);
    }

    // Kernel 2: fused pairwise kernel matrix (1D grid, XCD row-band decode)
    {
        dim3 grid(2048);
        dim3 block(BLK);
        nsm_matern_kernel<<<grid, block, 0, stream>>>(x, y, s_all, out);
    }
}